// Round 1
// baseline (220.665 us; speedup 1.0000x reference)
//
#include <hip/hip_runtime.h>

// Problem constants: B=8, MB=512, IN=1024, EMB=1024, H=16, KVH=4, HD=64, BS=16, K=32
//
// Algebra:
//  S[b,t,h,q]  = h[b,t] . (Wk_head(h/4) @ qr[q,h,:]) / 8        (qr = RoPE'd q)
//  VW[b,t,h,c] = h[b,t] . (Wv_head(h/4) @ (Wo@Wr)[h*64:(h+1)*64, c])
//  vel[b,m,q,c] = br[c] + sum_h [ sum_{t=m-31..m} E*VW ] / [ pad(m) + sum E ],  E=exp(S)
//  padded t<0: score 0 -> E=1 in denom, VW=0 in numer.

// ws layout (floats)
#define OFF_QR   0u          // [16][1024]          (q, h*64+d)
#define OFF_WOR  16384u      // [1024][2]
#define OFF_W1   18432u      // [1024][288]  cols: j<256 -> (q=j>>4,h=j&15); j>=256 -> h*2+c
#define OFF_S    313344u     // [b][q][h][512]   (t contiguous)
#define OFF_VW   1361920u    // [b][h*2+c][512]
// total 1492992 floats = 5.97 MB of d_ws

// ---------------- K1a: qr (RoPE'd query proj) + Wor = Wo @ Wr ----------------
__global__ __launch_bounds__(256) void k1a(
    const float* __restrict__ oq, const float* __restrict__ Wq,
    const float* __restrict__ fc, const float* __restrict__ fs,
    const float* __restrict__ Wo, const float* __restrict__ Wr,
    float* __restrict__ qr, float* __restrict__ Wor)
{
    __shared__ float sh[1024];
    __shared__ float shr[2048];
    const int blk = blockIdx.x;
    const int t = threadIdx.x;
    if (blk < 64) {
        const int q = blk >> 2, cg = blk & 3;
        for (int i = t; i < 1024; i += 256) sh[i] = oq[q * 1024 + i];
        __syncthreads();
        const int col = cg * 256 + t;
        const int h = col >> 6, d = col & 63;
        const int col2 = h * 64 + ((d < 32) ? (d + 32) : (d - 32));
        float a1 = 0.f, a2 = 0.f;
        for (int e = 0; e < 1024; ++e) {
            const float x = sh[e];
            a1 = fmaf(x, Wq[e * 1024 + col], a1);
            a2 = fmaf(x, Wq[e * 1024 + col2], a2);
        }
        const float c = fc[q * 64 + d], s = fs[q * 64 + d];
        const float rh = (d < 32) ? -a2 : a2;
        qr[q * 1024 + col] = fmaf(a1, c, rh * s);
    } else {
        for (int i = t; i < 2048; i += 256) shr[i] = Wr[i];
        __syncthreads();
        const int i = (blk - 64) * 128 + (t >> 1);
        const int c = t & 1;
        float acc = 0.f;
        for (int e = 0; e < 1024; ++e)
            acc = fmaf(Wo[i * 1024 + e], shr[e * 2 + c], acc);
        Wor[i * 2 + c] = acc;
    }
}

// ---------------- K1b: W1[i][288] = folded weights ----------------
__global__ __launch_bounds__(256) void k1b(
    const float* __restrict__ Wk, const float* __restrict__ Wv,
    const float* __restrict__ qr, const float* __restrict__ Wor,
    float* __restrict__ W1)
{
    __shared__ float kvsh[512];
    const int i = blockIdx.x;
    const int t = threadIdx.x;
    kvsh[t] = Wk[i * 256 + t];
    kvsh[256 + t] = Wv[i * 256 + t];
    __syncthreads();
    {
        const int q = t >> 4, h = t & 15;
        const float* qp = qr + q * 1024 + h * 64;
        const float* kp = kvsh + (h >> 2) * 64;
        float acc = 0.f;
        #pragma unroll 8
        for (int d = 0; d < 64; ++d) acc = fmaf(kp[d], qp[d], acc);
        W1[i * 288 + t] = acc * 0.125f;   // 1/sqrt(HD) folded in
    }
    if (t < 32) {
        const int h = t >> 1, c = t & 1;
        const float* vp = kvsh + 256 + (h >> 2) * 64;
        const float* wp = Wor + (h * 64) * 2 + c;
        float acc = 0.f;
        #pragma unroll 8
        for (int d = 0; d < 64; ++d) acc = fmaf(vp[d], wp[d * 2], acc);
        W1[i * 288 + 256 + t] = acc;
    }
}

// ---------------- K2: Y = h(4096x1024) @ W1(1024x288), scattered col-major out ----------------
__global__ __launch_bounds__(256) void k2(
    const float* __restrict__ A, const float* __restrict__ W1,
    float* __restrict__ Sarr, float* __restrict__ VWarr)
{
    __shared__ float As[32 * 68];   // [k][m], stride 68: b128 reads 2-way (free), scatter-writes 4-way
    __shared__ float Bs[32 * 36];   // [k][n], stride 36
    const int m0 = blockIdx.x * 64;
    const int n0 = blockIdx.y * 32;
    const int t = threadIdx.x;
    const int tm = t & 15, tn = t >> 4;
    const int a_kv = t & 7, a_m = t >> 3;       // A stage: float4 along k, rows a_m / a_m+32
    const int b_r = t >> 3, b_cg = t & 7;       // B stage: row k, float4 along n
    float acc[4][2] = {{0.f, 0.f}, {0.f, 0.f}, {0.f, 0.f}, {0.f, 0.f}};
    const float* Aptr0 = A + (size_t)(m0 + a_m) * 1024 + a_kv * 4;
    const float* Aptr1 = Aptr0 + 32 * 1024;
    const float* Bptr = W1 + (size_t)b_r * 288 + n0 + b_cg * 4;
    for (int k0 = 0; k0 < 1024; k0 += 32) {
        const float4 av0 = *(const float4*)(Aptr0 + k0);
        const float4 av1 = *(const float4*)(Aptr1 + k0);
        const float4 bv = *(const float4*)(Bptr + (size_t)k0 * 288);
        __syncthreads();
        As[(a_kv * 4 + 0) * 68 + a_m] = av0.x;
        As[(a_kv * 4 + 1) * 68 + a_m] = av0.y;
        As[(a_kv * 4 + 2) * 68 + a_m] = av0.z;
        As[(a_kv * 4 + 3) * 68 + a_m] = av0.w;
        As[(a_kv * 4 + 0) * 68 + a_m + 32] = av1.x;
        As[(a_kv * 4 + 1) * 68 + a_m + 32] = av1.y;
        As[(a_kv * 4 + 2) * 68 + a_m + 32] = av1.z;
        As[(a_kv * 4 + 3) * 68 + a_m + 32] = av1.w;
        *(float4*)(Bs + b_r * 36 + b_cg * 4) = bv;
        __syncthreads();
        #pragma unroll
        for (int k = 0; k < 32; ++k) {
            const float4 a = *(const float4*)(As + k * 68 + tm * 4);
            const float2 b = *(const float2*)(Bs + k * 36 + tn * 2);
            acc[0][0] = fmaf(a.x, b.x, acc[0][0]);
            acc[0][1] = fmaf(a.x, b.y, acc[0][1]);
            acc[1][0] = fmaf(a.y, b.x, acc[1][0]);
            acc[1][1] = fmaf(a.y, b.y, acc[1][1]);
            acc[2][0] = fmaf(a.z, b.x, acc[2][0]);
            acc[2][1] = fmaf(a.z, b.y, acc[2][1]);
            acc[3][0] = fmaf(a.w, b.x, acc[3][0]);
            acc[3][1] = fmaf(a.w, b.y, acc[3][1]);
        }
    }
    const int row0 = m0 + tm * 4;       // 4 consecutive t within one b (64-chunks never cross 512)
    const int bb = row0 >> 9;
    const int tt = row0 & 511;
    #pragma unroll
    for (int jj = 0; jj < 2; ++jj) {
        const int j = n0 + tn * 2 + jj;
        const float4 v = make_float4(acc[0][jj], acc[1][jj], acc[2][jj], acc[3][jj]);
        float* dst;
        if (j < 256)
            dst = Sarr + ((size_t)((bb * 16 + (j >> 4)) * 16 + (j & 15))) * 512 + tt;
        else
            dst = VWarr + ((size_t)(bb * 32 + (j - 256))) * 512 + tt;
        *(float4*)dst = v;   // col-major: coalesced across tm
    }
}

// ---------------- K3: exp + sliding-window softmax + head-reduce ----------------
#define PSTR 305   // 305%32==17: den reads conflict-free, EV reads 2-way (free)
__global__ __launch_bounds__(256) void k3(
    const float* __restrict__ Sarr, const float* __restrict__ VWarr,
    const float* __restrict__ brp, float* __restrict__ out)
{
    __shared__ float Es[16 * PSTR];
    __shared__ float EVs[32 * PSTR];
    const int b = blockIdx.x, q = blockIdx.y, half = blockIdx.z;
    const int tbase = half * 256;
    const int tid = threadIdx.x;
    for (int idx = tid; idx < 16 * 287; idx += 256) {
        const int h = idx / 287;
        const int tl = idx - h * 287;
        const int tt = tbase - 31 + tl;
        float e = 1.f, ev0 = 0.f, ev1 = 0.f;    // padded: score 0 -> E=1, V=0 -> EV=0
        if (tt >= 0) {
            const float s = Sarr[((size_t)((b * 16 + q) * 16 + h)) * 512 + tt];
            e = __expf(s);
            ev0 = e * VWarr[((size_t)(b * 32 + 2 * h)) * 512 + tt];
            ev1 = e * VWarr[((size_t)(b * 32 + 2 * h + 1)) * 512 + tt];
        }
        Es[h * PSTR + tl] = e;
        EVs[(2 * h) * PSTR + tl] = ev0;
        EVs[(2 * h + 1) * PSTR + tl] = ev1;
    }
    __syncthreads();
    const int h = tid & 15, mg = tid >> 4;   // thread = (head, 16-m group); h-groups = lane groups
    const float* ep = Es + h * PSTR + mg * 16;
    const float* e0 = EVs + (2 * h) * PSTR + mg * 16;
    const float* e1 = EVs + (2 * h + 1) * PSTR + mg * 16;
    float den = 0.f, n0 = 0.f, n1 = 0.f;
    #pragma unroll
    for (int s = 0; s < 32; ++s) { den += ep[s]; n0 += e0[s]; n1 += e1[s]; }
    const float br0 = brp[0], br1 = brp[1];
    for (int u = 0; u < 16; ++u) {
        const float inv = 1.f / den;
        float c0 = n0 * inv, c1 = n1 * inv;
        #pragma unroll
        for (int w = 1; w < 16; w <<= 1) {    // butterfly over the 16 head-lanes
            c0 += __shfl_xor(c0, w, 64);
            c1 += __shfl_xor(c1, w, 64);
        }
        if (h == 0) {
            const int m = tbase + mg * 16 + u;
            float* o = out + ((size_t)((b * 512 + m) * 16 + q)) * 2;
            o[0] = c0 + br0;
            o[1] = c1 + br1;
        }
        if (u < 15) {
            den += ep[u + 32] - ep[u];
            n0 += e0[u + 32] - e0[u];
            n1 += e1[u + 32] - e1[u];
        }
    }
}

extern "C" void kernel_launch(void* const* d_in, const int* in_sizes, int n_in,
                              void* d_out, int out_size, void* d_ws, size_t ws_size,
                              hipStream_t stream)
{
    (void)in_sizes; (void)n_in; (void)out_size; (void)ws_size;
    const float* h  = (const float*)d_in[0];
    const float* fc = (const float*)d_in[1];
    const float* fs = (const float*)d_in[2];
    const float* Wq = (const float*)d_in[3];
    const float* Wk = (const float*)d_in[4];
    const float* Wv = (const float*)d_in[5];
    const float* Wo = (const float*)d_in[6];
    const float* oq = (const float*)d_in[7];
    const float* Wr = (const float*)d_in[8];
    const float* br = (const float*)d_in[9];
    float* ws = (float*)d_ws;
    float* qr    = ws + OFF_QR;
    float* Wor   = ws + OFF_WOR;
    float* W1    = ws + OFF_W1;
    float* Sarr  = ws + OFF_S;
    float* VWarr = ws + OFF_VW;
    float* out = (float*)d_out;

    hipLaunchKernelGGL(k1a, dim3(72), dim3(256), 0, stream, oq, Wq, fc, fs, Wo, Wr, qr, Wor);
    hipLaunchKernelGGL(k1b, dim3(1024), dim3(256), 0, stream, Wk, Wv, qr, Wor, W1);
    hipLaunchKernelGGL(k2, dim3(64, 9), dim3(256), 0, stream, h, W1, Sarr, VWarr);
    hipLaunchKernelGGL(k3, dim3(8, 16, 2), dim3(256), 0, stream, Sarr, VWarr, br, out);
}

// Round 3
// 154.329 us; speedup vs baseline: 1.4298x; 1.4298x over previous
//
#include <hip/hip_runtime.h>

// B=8, MB=512, IN=1024, EMB=1024, H=16, KVH=4, HD=64, BS=16, K=32
//
// S[b,t,h,q]  = h[b,t] . (Wk_head @ qr[q,h,:]) / 8
// VW[b,t,h,c] = h[b,t] . (Wv_head @ (Wo@Wr)[h*64:(h+1)*64, c])
// vel[b,m,q,c] = br[c] + sum_h [win-sum E*VW] / [win-sum E],  E=exp(S), window t in [m-31,m]
// pad t<0: S=0 -> E=1 in denom, VW=0 in numer  (handled by zeroed left-pad of 32)

// ws layout (floats)
#define OFF_PART 0u          // [16 ec][16 q][1024 col]  e-split partials of oq@Wq
#define OFF_WOR  262144u     // [1024][2]
#define OFF_QR   264192u     // [16][1024]
#define OFF_W1   280576u     // [1024][320]  cols: j<256 -> (q=j>>4,h=j&15); 256..287 -> h*2+c; 288..319 zero
#define OFF_S0   608256u     // [b*16*16 rows][544]  row=((b*16+q)*16+h), data at [32..544)
#define OFF_S1   1722368u
#define OFF_VW0  2836480u    // [b*32 rows][544]  row=b*32+(h*2+c)
#define OFF_VW1  2975744u
// total 3115008 floats = 12.46 MB

#define SROW 544

// ---------------- kA: blocks 0..255: e-split oq@Wq partials; 256..511: Wor = Wo@Wr ----------
__global__ __launch_bounds__(256) void kA(
    const float* __restrict__ oq, const float* __restrict__ Wq,
    const float* __restrict__ Wo, const float* __restrict__ Wr,
    float* __restrict__ part, float* __restrict__ Wor)
{
    __shared__ float sm[5376];   // kq: oqs[1024] + red[4352]; kwor: shr[2048]
    const int b = blockIdx.x;
    const int t = threadIdx.x;
    if (b < 256) {
        const int ec = b >> 4, cc = b & 15;
        // stage oq chunk: oqs[q*64 + el]
        #pragma unroll
        for (int j = 0; j < 4; ++j) {
            const int idx = t + 256 * j;
            sm[idx] = oq[(idx >> 6) * 1024 + ec * 64 + (idx & 63)];
        }
        __syncthreads();
        const int eg = t >> 6, lane = t & 63;
        const int col = cc * 64 + lane;
        float acc[16];
        #pragma unroll
        for (int q = 0; q < 16; ++q) acc[q] = 0.f;
        const float* wq = Wq + (size_t)(ec * 64 + eg * 16) * 1024 + col;
        const float* o = sm + eg * 16;
        for (int j = 0; j < 16; ++j) {
            const float w = wq[(size_t)j * 1024];
            #pragma unroll
            for (int q = 0; q < 16; ++q)
                acc[q] = fmaf(w, o[q * 64 + j], acc[q]);
        }
        float* red = sm + 1024;
        __syncthreads();   // protect oqs until all reads done
        #pragma unroll
        for (int q = 0; q < 16; ++q)
            red[eg * 1088 + lane * 17 + q] = acc[q];
        __syncthreads();
        #pragma unroll
        for (int j = 0; j < 4; ++j) {
            const int o2 = t + 256 * j;
            const int q = o2 >> 6, l = o2 & 63;
            float s = red[l * 17 + q] + red[1088 + l * 17 + q]
                    + red[2176 + l * 17 + q] + red[3264 + l * 17 + q];
            part[(size_t)ec * 16384 + q * 1024 + cc * 64 + l] = s;
        }
    } else {
        // Wor = Wo @ Wr  (4 rows per block, wave per row)
        #pragma unroll
        for (int j = 0; j < 8; ++j) sm[t + 256 * j] = Wr[t + 256 * j];
        __syncthreads();
        const int i = (b - 256) * 4 + (t >> 6);
        const int lane = t & 63;
        float a0 = 0.f, a1 = 0.f;
        const float* wo = Wo + (size_t)i * 1024 + lane;
        #pragma unroll
        for (int j = 0; j < 16; ++j) {
            const float w = wo[j * 64];
            const int e = lane + j * 64;
            a0 = fmaf(w, sm[2 * e], a0);
            a1 = fmaf(w, sm[2 * e + 1], a1);
        }
        #pragma unroll
        for (int w = 1; w < 64; w <<= 1) {
            a0 += __shfl_xor(a0, w, 64);
            a1 += __shfl_xor(a1, w, 64);
        }
        if (lane == 0) { Wor[i * 2] = a0; Wor[i * 2 + 1] = a1; }
    }
}

// ---------------- kB: blocks 0..63: RoPE(sum partials) -> qr; rest: zero pads ----------------
__global__ __launch_bounds__(256) void kB(
    const float* __restrict__ part, const float* __restrict__ fc, const float* __restrict__ fs,
    float* __restrict__ qr, float* __restrict__ S0, float* __restrict__ S1,
    float* __restrict__ VW0, float* __restrict__ VW1)
{
    const int b = blockIdx.x;
    const int t = threadIdx.x;
    if (b < 64) {
        const int idx = b * 256 + t;          // [0, 16384)
        const int q = idx >> 10, col = idx & 1023;
        const int h = col >> 6, d = col & 63;
        const int col2 = h * 64 + ((d < 32) ? (d + 32) : (d - 32));
        float a1 = 0.f, a2 = 0.f;
        #pragma unroll
        for (int ec = 0; ec < 16; ++ec) {
            a1 += part[(size_t)ec * 16384 + q * 1024 + col];
            a2 += part[(size_t)ec * 16384 + q * 1024 + col2];
        }
        const float c = fc[q * 64 + d], s = fs[q * 64 + d];
        const float rh = (d < 32) ? -a2 : a2;
        qr[q * 1024 + col] = fmaf(a1, c, rh * s);
    } else if (b < 320) {
        const int pidx = (b - 64) * 256 + t;  // S0 pads: 2048 rows x 32
        S0[(size_t)(pidx >> 5) * SROW + (pidx & 31)] = 0.f;
    } else if (b < 576) {
        const int pidx = (b - 320) * 256 + t;
        S1[(size_t)(pidx >> 5) * SROW + (pidx & 31)] = 0.f;
    } else if (b < 608) {
        const int pidx = (b - 576) * 256 + t; // VW0 pads: 256 rows x 32
        VW0[(size_t)(pidx >> 5) * SROW + (pidx & 31)] = 0.f;
    } else {
        const int pidx = (b - 608) * 256 + t;
        VW1[(size_t)(pidx >> 5) * SROW + (pidx & 31)] = 0.f;
    }
}

// ---------------- k1b: W1[i][320] folded weights, 4 rows/block, LDS-staged qr ----------------
__global__ __launch_bounds__(256) void k1b(
    const float* __restrict__ Wk, const float* __restrict__ Wv,
    const float* __restrict__ qr, const float* __restrict__ Wor,
    float* __restrict__ W1)
{
    __shared__ float qs[16384];   // 64KB
    __shared__ float kvs[2048];   // Wk rows [0..1024), Wv rows [1024..2048)
    __shared__ float wors[2048];
    const int i0 = blockIdx.x * 4;
    const int t = threadIdx.x;
    #pragma unroll
    for (int j = 0; j < 16; ++j)
        ((float4*)qs)[t + 256 * j] = ((const float4*)qr)[t + 256 * j];
    ((float4*)kvs)[t] = ((const float4*)(Wk + (size_t)i0 * 256))[t];
    ((float4*)(kvs + 1024))[t] = ((const float4*)(Wv + (size_t)i0 * 256))[t];
    #pragma unroll
    for (int j = 0; j < 2; ++j)
        ((float4*)wors)[t + 256 * j] = ((const float4*)Wor)[t + 256 * j];
    __syncthreads();
    const int q = t >> 4, hh = t & 15;
    const int rot = t & 63;
    const float* qp = qs + q * 1024 + hh * 64;
    for (int r = 0; r < 4; ++r) {
        const float* kp = kvs + r * 256 + (hh >> 2) * 64;
        float acc = 0.f;
        #pragma unroll 8
        for (int dd = 0; dd < 64; ++dd) {
            const int d = (dd + rot) & 63;
            acc = fmaf(kp[d], qp[d], acc);
        }
        W1[(size_t)(i0 + r) * 320 + t] = acc * 0.125f;
        if (t < 32) {
            const int h2 = t >> 1, c = t & 1;
            const float* vp = kvs + 1024 + r * 256 + (h2 >> 2) * 64;
            float va = 0.f;
            #pragma unroll 8
            for (int dd = 0; dd < 64; ++dd) {
                const int d = (dd + rot) & 63;
                va = fmaf(vp[d], wors[(h2 * 64 + d) * 2 + c], va);
            }
            W1[(size_t)(i0 + r) * 320 + 256 + t] = va;
        } else if (t < 64) {
            W1[(size_t)(i0 + r) * 320 + 256 + t] = 0.f;   // zero pad cols 288..319
        }
    }
}

// ---------------- k2: Y = h(4096x1024) @ W1(1024x320), tile 64x64, K-split 2 ----------------
__global__ __launch_bounds__(256) void k2(
    const float* __restrict__ A, const float* __restrict__ W1,
    float* __restrict__ S0, float* __restrict__ S1,
    float* __restrict__ VW0, float* __restrict__ VW1)
{
    __shared__ float As[32 * 68];   // [k][m]
    __shared__ float Bs[32 * 68];   // [k][n]
    const int m0 = blockIdx.x * 64;
    const int n0 = blockIdx.y * 64;
    const int kh = blockIdx.z;
    const int t = threadIdx.x;
    const int tm = t & 15, tn = t >> 4;
    const int a_kv = t & 7, a_m = t >> 3;
    const int b_r = t >> 4;            // B stage: rows b_r and b_r+16
    const int b_c = (t & 15) * 4;      // full 64-col coverage
    float acc[4][4];
    #pragma unroll
    for (int i = 0; i < 4; ++i)
        #pragma unroll
        for (int j = 0; j < 4; ++j) acc[i][j] = 0.f;
    const float* Aptr0 = A + (size_t)(m0 + a_m) * 1024 + kh * 512 + a_kv * 4;
    const float* Aptr1 = Aptr0 + 32 * 1024;
    const float* Bptr0 = W1 + (size_t)(kh * 512 + b_r) * 320 + n0 + b_c;
    const float* Bptr1 = Bptr0 + (size_t)16 * 320;
    for (int k0 = 0; k0 < 512; k0 += 32) {
        const float4 av0 = *(const float4*)(Aptr0 + k0);
        const float4 av1 = *(const float4*)(Aptr1 + k0);
        const float4 bv0 = *(const float4*)(Bptr0 + (size_t)k0 * 320);
        const float4 bv1 = *(const float4*)(Bptr1 + (size_t)k0 * 320);
        __syncthreads();
        As[(a_kv * 4 + 0) * 68 + a_m] = av0.x;
        As[(a_kv * 4 + 1) * 68 + a_m] = av0.y;
        As[(a_kv * 4 + 2) * 68 + a_m] = av0.z;
        As[(a_kv * 4 + 3) * 68 + a_m] = av0.w;
        As[(a_kv * 4 + 0) * 68 + a_m + 32] = av1.x;
        As[(a_kv * 4 + 1) * 68 + a_m + 32] = av1.y;
        As[(a_kv * 4 + 2) * 68 + a_m + 32] = av1.z;
        As[(a_kv * 4 + 3) * 68 + a_m + 32] = av1.w;
        *(float4*)(Bs + b_r * 68 + b_c) = bv0;
        *(float4*)(Bs + (b_r + 16) * 68 + b_c) = bv1;
        __syncthreads();
        #pragma unroll
        for (int k = 0; k < 32; ++k) {
            const float4 a = *(const float4*)(As + k * 68 + tm * 4);
            const float4 bq = *(const float4*)(Bs + k * 68 + tn * 4);
            const float bb[4] = {bq.x, bq.y, bq.z, bq.w};
            #pragma unroll
            for (int jj = 0; jj < 4; ++jj) {
                acc[0][jj] = fmaf(a.x, bb[jj], acc[0][jj]);
                acc[1][jj] = fmaf(a.y, bb[jj], acc[1][jj]);
                acc[2][jj] = fmaf(a.z, bb[jj], acc[2][jj]);
                acc[3][jj] = fmaf(a.w, bb[jj], acc[3][jj]);
            }
        }
    }
    float* Sh  = kh ? S1 : S0;
    float* VWh = kh ? VW1 : VW0;
    const int m = m0 + tm * 4;
    const int bb2 = m >> 9;
    const int tt = m & 511;
    #pragma unroll
    for (int jj = 0; jj < 4; ++jj) {
        const int j = n0 + tn * 4 + jj;
        if (j >= 288) continue;
        const float4 v = make_float4(acc[0][jj], acc[1][jj], acc[2][jj], acc[3][jj]);
        float* dst;
        if (j < 256)
            dst = Sh + (size_t)((bb2 * 16 + (j >> 4)) * 16 + (j & 15)) * SROW + 32 + tt;
        else
            dst = VWh + (size_t)(bb2 * 32 + (j - 256)) * SROW + 32 + tt;
        *(float4*)dst = v;
    }
}

// ---------------- k3: exp + sliding-window softmax + head-reduce ----------------
#define ES 324
__global__ __launch_bounds__(256) void k3(
    const float* __restrict__ S0, const float* __restrict__ S1,
    const float* __restrict__ VW0, const float* __restrict__ VW1,
    const float* __restrict__ brp, float* __restrict__ out)
{
    __shared__ float Es[16 * ES];
    __shared__ float EVs[32 * ES];
    const int b = blockIdx.x, q = blockIdx.y, half = blockIdx.z;
    const int tbase = half * 256;
    const int tid = threadIdx.x;
    // phase 1: Es[h][wi] = exp(S0+S1), wi in [0,288) (max consumed index is 287)
    for (int idx = tid; idx < 16 * 72; idx += 256) {
        const int h = idx / 72, g = idx - h * 72;
        const size_t off = (size_t)((b * 16 + q) * 16 + h) * SROW + tbase + g * 4;
        const float4 a = *(const float4*)(S0 + off);
        const float4 c = *(const float4*)(S1 + off);
        float4 e;
        e.x = __expf(a.x + c.x); e.y = __expf(a.y + c.y);
        e.z = __expf(a.z + c.z); e.w = __expf(a.w + c.w);
        *(float4*)(Es + h * ES + g * 4) = e;
    }
    __syncthreads();
    // phase 2: EVs[hc][wi] = Es[h][wi] * (VW0+VW1)
    for (int idx = tid; idx < 32 * 72; idx += 256) {
        const int hc = idx / 72, g = idx - hc * 72;
        const size_t off = (size_t)(b * 32 + hc) * SROW + tbase + g * 4;
        const float4 v0 = *(const float4*)(VW0 + off);
        const float4 v1 = *(const float4*)(VW1 + off);
        const float4 e = *(const float4*)(Es + (hc >> 1) * ES + g * 4);
        float4 r;
        r.x = e.x * (v0.x + v1.x); r.y = e.y * (v0.y + v1.y);
        r.z = e.z * (v0.z + v1.z); r.w = e.w * (v0.w + v1.w);
        *(float4*)(EVs + hc * ES + g * 4) = r;
    }
    __syncthreads();
    const int h = tid & 15, mg = tid >> 4;
    const float* ep = Es + h * ES + mg * 16;
    const float* e0 = EVs + (2 * h) * ES + mg * 16;
    const float* e1 = EVs + (2 * h + 1) * ES + mg * 16;
    float den = 0.f, n0 = 0.f, n1 = 0.f;
    #pragma unroll
    for (int s = 0; s < 32; ++s) {      // bank-rotated by 2h: conflict-light
        const int ss = 1 + ((s + 2 * h) & 31);
        den += ep[ss]; n0 += e0[ss]; n1 += e1[ss];
    }
    const float br0 = brp[0], br1 = brp[1];
    for (int u = 0; u < 16; ++u) {
        const float inv = 1.f / den;
        float c0 = n0 * inv, c1 = n1 * inv;
        #pragma unroll
        for (int w = 1; w < 16; w <<= 1) {
            c0 += __shfl_xor(c0, w, 64);
            c1 += __shfl_xor(c1, w, 64);
        }
        if (h == 0) {
            const int m = tbase + mg * 16 + u;
            float* o = out + (size_t)((b * 512 + m) * 16 + q) * 2;
            o[0] = c0 + br0;
            o[1] = c1 + br1;
        }
        if (u < 15) {
            den += ep[33 + u] - ep[1 + u];
            n0 += e0[33 + u] - e0[1 + u];
            n1 += e1[33 + u] - e1[1 + u];
        }
    }
}

extern "C" void kernel_launch(void* const* d_in, const int* in_sizes, int n_in,
                              void* d_out, int out_size, void* d_ws, size_t ws_size,
                              hipStream_t stream)
{
    (void)in_sizes; (void)n_in; (void)out_size; (void)ws_size;
    const float* h  = (const float*)d_in[0];
    const float* fc = (const float*)d_in[1];
    const float* fs = (const float*)d_in[2];
    const float* Wq = (const float*)d_in[3];
    const float* Wk = (const float*)d_in[4];
    const float* Wv = (const float*)d_in[5];
    const float* Wo = (const float*)d_in[6];
    const float* oq = (const float*)d_in[7];
    const float* Wr = (const float*)d_in[8];
    const float* br = (const float*)d_in[9];
    float* ws = (float*)d_ws;
    float* part = ws + OFF_PART;
    float* Wor  = ws + OFF_WOR;
    float* qr   = ws + OFF_QR;
    float* W1   = ws + OFF_W1;
    float* S0   = ws + OFF_S0;
    float* S1   = ws + OFF_S1;
    float* VW0  = ws + OFF_VW0;
    float* VW1  = ws + OFF_VW1;
    float* out = (float*)d_out;

    hipLaunchKernelGGL(kA,  dim3(512), dim3(256), 0, stream, oq, Wq, Wo, Wr, part, Wor);
    hipLaunchKernelGGL(kB,  dim3(640), dim3(256), 0, stream, part, fc, fs, qr, S0, S1, VW0, VW1);
    hipLaunchKernelGGL(k1b, dim3(256), dim3(256), 0, stream, Wk, Wv, qr, Wor, W1);
    hipLaunchKernelGGL(k2,  dim3(64, 5, 2), dim3(256), 0, stream, h, W1, S0, S1, VW0, VW1);
    hipLaunchKernelGGL(k3,  dim3(8, 16, 2), dim3(256), 0, stream, S0, S1, VW0, VW1, br, out);
}

// Round 4
// 131.127 us; speedup vs baseline: 1.6828x; 1.1769x over previous
//
#include <hip/hip_runtime.h>

// B=8, MB=512, IN=1024, EMB=1024, H=16, KVH=4, HD=64, BS=16, K=32
//
// S[b,t,h,q]  = h[b,t] . (Wk_head @ qr[q,h,:]) / 8
// VW[b,t,h,c] = h[b,t] . (Wv_head @ (Wo@Wr)[h*64:(h+1)*64, c])
// vel[b,m,q,c] = br[c] + sum_h [win-sum E*VW] / [win-sum E],  E=exp(S)
// The 4096x1024x288 GEMM runs as split-bf16 MFMA: X = Xh + Xl (trunc split),
// C = Ah*Bh + Ah*Bl + Al*Bh  (Al*Bl ~2^-16 rel, dropped).

typedef __attribute__((ext_vector_type(8))) short v8s;
typedef __attribute__((ext_vector_type(4))) float v4f;

// ws layout (floats)
#define OFF_WOR  0u          // [1024][2]
#define OFF_QR   2048u       // [16][1024]
#define OFF_WTH  18432u      // bf16 hi, transposed [320 j][1024 i]  (163840 floats)
#define OFF_WTL  182272u     // bf16 lo
#define OFF_S0   346112u     // [2048 rows][544]  row=((b*16+q)*16+h), data at [32..544)
#define OFF_S1   1460224u
#define OFF_VW0  2574336u    // [256 rows][544]   row=b*32+(h*2+c)
#define OFF_VW1  2713600u
// total 2852864 floats = 11.41 MB

#define SROW 544

__device__ __forceinline__ void split_bf16(float a, unsigned short& h, unsigned short& l) {
    const unsigned u = __float_as_uint(a);
    h = (unsigned short)(u >> 16);
    const float r = a - __uint_as_float(u & 0xFFFF0000u);   // exact residual
    unsigned v = __float_as_uint(r);
    v += 0x7FFFu + ((v >> 16) & 1u);                        // RNE to bf16
    l = (unsigned short)(v >> 16);
}

// ---------------- kP: qr (proj+RoPE) | Wor = Wo@Wr | zero pads ----------------
__global__ __launch_bounds__(256) void kP(
    const float* __restrict__ oq, const float* __restrict__ Wq,
    const float* __restrict__ fc, const float* __restrict__ fs,
    const float* __restrict__ Wo, const float* __restrict__ Wr,
    float* __restrict__ qr, float* __restrict__ Wor,
    float* __restrict__ S0, float* __restrict__ S1,
    float* __restrict__ VW0, float* __restrict__ VW1,
    unsigned* __restrict__ wthu, unsigned* __restrict__ wtlu)
{
    __shared__ float sm[2048];
    const int b = blockIdx.x, t = threadIdx.x;
    if (b < 256) {
        // one (q, head) pair: 64 output cols; e-split across 4 waves
        const int q = b >> 4, h = b & 15;
        #pragma unroll
        for (int j = 0; j < 4; ++j) sm[t + 256 * j] = oq[q * 1024 + t + 256 * j];
        __syncthreads();
        const int w = t >> 6, lane = t & 63;
        const float* wq = Wq + (size_t)(w * 256) * 1024 + h * 64 + lane;
        const float* os = sm + w * 256;
        float acc = 0.f;
        #pragma unroll 8
        for (int e = 0; e < 256; ++e) acc = fmaf(os[e], wq[(size_t)e * 1024], acc);
        sm[1024 + w * 64 + lane] = acc;
        __syncthreads();
        if (t < 64) {
            const int d = t, p = d ^ 32;
            const float a1 = sm[1024 + d] + sm[1088 + d] + sm[1152 + d] + sm[1216 + d];
            const float a2 = sm[1024 + p] + sm[1088 + p] + sm[1152 + p] + sm[1216 + p];
            const float c = fc[q * 64 + d], s = fs[q * 64 + d];
            const float rh = (d < 32) ? -a2 : a2;
            qr[q * 1024 + h * 64 + d] = fmaf(a1, c, rh * s);
        }
    } else if (b < 512) {
        // Wor = Wo @ Wr  (4 rows/block, wave per row)
        #pragma unroll
        for (int j = 0; j < 8; ++j) sm[t + 256 * j] = Wr[t + 256 * j];
        __syncthreads();
        const int i = (b - 256) * 4 + (t >> 6);
        const int lane = t & 63;
        float a0 = 0.f, a1 = 0.f;
        const float* wo = Wo + (size_t)i * 1024 + lane;
        #pragma unroll
        for (int j = 0; j < 16; ++j) {
            const float w = wo[j * 64];
            const int e = lane + j * 64;
            a0 = fmaf(w, sm[2 * e], a0);
            a1 = fmaf(w, sm[2 * e + 1], a1);
        }
        #pragma unroll
        for (int w = 1; w < 64; w <<= 1) {
            a0 += __shfl_xor(a0, w, 64);
            a1 += __shfl_xor(a1, w, 64);
        }
        if (lane == 0) { Wor[i * 2] = a0; Wor[i * 2 + 1] = a1; }
    } else if (b < 656) {
        // zero left-pads (32 floats = 8 float4 per row)
        const int idx = (b - 512) * 256 + t;  // < 36864
        const float4 z = make_float4(0.f, 0.f, 0.f, 0.f);
        if (idx < 16384)       *(float4*)(S0  + (size_t)(idx >> 3) * SROW + (idx & 7) * 4) = z;
        else if (idx < 32768)  *(float4*)(S1  + (size_t)((idx - 16384) >> 3) * SROW + (idx & 7) * 4) = z;
        else if (idx < 34816)  *(float4*)(VW0 + (size_t)((idx - 32768) >> 3) * SROW + (idx & 7) * 4) = z;
        else                   *(float4*)(VW1 + (size_t)((idx - 34816) >> 3) * SROW + (idx & 7) * 4) = z;
    } else {
        // zero Wt pad rows 288..319 (16384 u32 per array)
        unsigned* dst = (b == 656) ? wthu : wtlu;
        #pragma unroll
        for (int j = 0; j < 64; ++j) dst[147456 + t + 256 * j] = 0u;
    }
}

// ---------------- kW: folded weights -> Wth/Wtl bf16 transposed [j][i] ----------------
// per kv-group g: (32i x 64d Wk|Wv) @ (64d x 72jc [qr-cols | v-cols])
__global__ __launch_bounds__(256) void kW(
    const float* __restrict__ Wk, const float* __restrict__ Wv,
    const float* __restrict__ qr, const float* __restrict__ Wor,
    unsigned short* __restrict__ Wth, unsigned short* __restrict__ Wtl)
{
    __shared__ float As[32 * 68];
    __shared__ float Bt[72 * 68];   // [jc][d]
    const int b = blockIdx.x, t = threadIdx.x;
    const int g = b >> 5, i0 = (b & 31) * 32;
    // stage Bt qr-part: Bt[q*4+hh][d] = qr[q][ (4g+hh)*64 + d ]
    #pragma unroll
    for (int jj = 0; jj < 16; ++jj) {
        const int i2 = t + 256 * jj;
        const int d = i2 & 63, col = i2 >> 6;
        Bt[col * 68 + d] = qr[(col >> 2) * 1024 + (g * 4 + (col & 3)) * 64 + d];
    }
    // stage Bt v-part: Bt[64 + hh*2+c][d] = Wor[(4g+hh)*64+d][c]
    #pragma unroll
    for (int jj = 0; jj < 2; ++jj) {
        const int i2 = t + 256 * jj;
        const int d = i2 & 63, vc = i2 >> 6;
        Bt[(64 + vc) * 68 + d] = Wor[((g * 4 + (vc >> 1)) * 64 + d) * 2 + (vc & 1)];
    }
    // stage A = Wk rows
    {
        const int i = t >> 3, dc = (t & 7) * 8;
        const float* src = Wk + (size_t)(i0 + i) * 256 + g * 64 + dc;
        *(float4*)&As[i * 68 + dc] = *(const float4*)src;
        *(float4*)&As[i * 68 + dc + 4] = *(const float4*)(src + 4);
    }
    __syncthreads();
    const int jc = t & 63, iq = t >> 6;
    {
        float out[8];
        #pragma unroll
        for (int r = 0; r < 8; ++r) out[r] = 0.f;
        #pragma unroll
        for (int dc = 0; dc < 16; ++dc) {
            const float4 bv = *(const float4*)&Bt[jc * 68 + dc * 4];
            #pragma unroll
            for (int r = 0; r < 8; ++r) {
                const float4 av = *(const float4*)&As[(iq * 8 + r) * 68 + dc * 4];
                out[r] = fmaf(av.x, bv.x, out[r]);
                out[r] = fmaf(av.y, bv.y, out[r]);
                out[r] = fmaf(av.z, bv.z, out[r]);
                out[r] = fmaf(av.w, bv.w, out[r]);
            }
        }
        const int j = (jc >> 2) * 16 + g * 4 + (jc & 3);
        v8s ph, pl;
        #pragma unroll
        for (int r = 0; r < 8; ++r) {
            unsigned short hh, ll;
            split_bf16(out[r] * 0.125f, hh, ll);   // 1/sqrt(HD) folded in
            ph[r] = (short)hh; pl[r] = (short)ll;
        }
        *(v8s*)&Wth[(size_t)j * 1024 + i0 + iq * 8] = ph;
        *(v8s*)&Wtl[(size_t)j * 1024 + i0 + iq * 8] = pl;
    }
    __syncthreads();
    // restage A = Wv rows
    {
        const int i = t >> 3, dc = (t & 7) * 8;
        const float* src = Wv + (size_t)(i0 + i) * 256 + g * 64 + dc;
        *(float4*)&As[i * 68 + dc] = *(const float4*)src;
        *(float4*)&As[i * 68 + dc + 4] = *(const float4*)(src + 4);
    }
    __syncthreads();
    {
        const int il = t >> 3, vc = t & 7;
        float acc = 0.f;
        #pragma unroll
        for (int dc = 0; dc < 16; ++dc) {
            const float4 av = *(const float4*)&As[il * 68 + dc * 4];
            const float4 bv = *(const float4*)&Bt[(64 + vc) * 68 + dc * 4];
            acc = fmaf(av.x, bv.x, acc);
            acc = fmaf(av.y, bv.y, acc);
            acc = fmaf(av.z, bv.z, acc);
            acc = fmaf(av.w, bv.w, acc);
        }
        const int j = 256 + (g * 4 + (vc >> 1)) * 2 + (vc & 1);
        unsigned short hh, ll;
        split_bf16(acc, hh, ll);
        Wth[(size_t)j * 1024 + i0 + il] = hh;
        Wtl[(size_t)j * 1024 + i0 + il] = ll;
    }
}

// ---------------- k2: split-bf16 MFMA GEMM, tile 64x64, K-split 2 ----------------
__global__ __launch_bounds__(256) void k2(
    const float* __restrict__ A,
    const unsigned short* __restrict__ Wth, const unsigned short* __restrict__ Wtl,
    float* __restrict__ S0, float* __restrict__ S1,
    float* __restrict__ VW0, float* __restrict__ VW1)
{
    __shared__ unsigned short Ah[64 * 40], Al[64 * 40];   // [m][k], stride 40 shorts (16B-aligned rows)
    __shared__ unsigned short Bh[64 * 40], Bl[64 * 40];   // [n][k]
    const int m0 = blockIdx.x * 64;
    const int n0 = blockIdx.y * 64;
    const int kh = blockIdx.z;
    const int t = threadIdx.x;
    const int lane = t & 63, wv = t >> 6;
    const int l16 = lane & 15, quad = lane >> 4;
    const int wm = wv >> 1, wn = wv & 1;
    const int sr = t >> 2, kc = (t & 3) * 8;
    v4f acc[2][2];
    #pragma unroll
    for (int i = 0; i < 2; ++i)
        #pragma unroll
        for (int j = 0; j < 2; ++j) acc[i][j] = (v4f)(0.f);
    const float* Ap = A + (size_t)(m0 + sr) * 1024 + kh * 512 + kc;
    const unsigned short* Bph = Wth + (size_t)(n0 + sr) * 1024 + kh * 512 + kc;
    const unsigned short* Bpl = Wtl + (size_t)(n0 + sr) * 1024 + kh * 512 + kc;
    for (int k0 = 0; k0 < 512; k0 += 32) {
        const float4 a0 = *(const float4*)(Ap + k0);
        const float4 a1 = *(const float4*)(Ap + k0 + 4);
        const v8s bhv = *(const v8s*)(Bph + k0);
        const v8s blv = *(const v8s*)(Bpl + k0);
        v8s ahv, alv;
        {
            const float af[8] = {a0.x, a0.y, a0.z, a0.w, a1.x, a1.y, a1.z, a1.w};
            #pragma unroll
            for (int j = 0; j < 8; ++j) {
                unsigned short hh, ll;
                split_bf16(af[j], hh, ll);
                ahv[j] = (short)hh; alv[j] = (short)ll;
            }
        }
        __syncthreads();
        *(v8s*)&Ah[sr * 40 + kc] = ahv;
        *(v8s*)&Al[sr * 40 + kc] = alv;
        *(v8s*)&Bh[sr * 40 + kc] = bhv;
        *(v8s*)&Bl[sr * 40 + kc] = blv;
        __syncthreads();
        v8s fah[2], fal[2], fbh[2], fbl[2];
        #pragma unroll
        for (int s = 0; s < 2; ++s) {
            const int mr = wm * 32 + s * 16 + l16;
            fah[s] = *(const v8s*)&Ah[mr * 40 + quad * 8];
            fal[s] = *(const v8s*)&Al[mr * 40 + quad * 8];
            const int nr = wn * 32 + s * 16 + l16;
            fbh[s] = *(const v8s*)&Bh[nr * 40 + quad * 8];
            fbl[s] = *(const v8s*)&Bl[nr * 40 + quad * 8];
        }
        #pragma unroll
        for (int ms = 0; ms < 2; ++ms)
            #pragma unroll
            for (int ns = 0; ns < 2; ++ns) {
                acc[ms][ns] = __builtin_amdgcn_mfma_f32_16x16x32_bf16(fal[ms], fbh[ns], acc[ms][ns], 0, 0, 0);
                acc[ms][ns] = __builtin_amdgcn_mfma_f32_16x16x32_bf16(fah[ms], fbl[ns], acc[ms][ns], 0, 0, 0);
                acc[ms][ns] = __builtin_amdgcn_mfma_f32_16x16x32_bf16(fah[ms], fbh[ns], acc[ms][ns], 0, 0, 0);
            }
    }
    float* Sh  = kh ? S1 : S0;
    float* VWh = kh ? VW1 : VW0;
    #pragma unroll
    for (int ms = 0; ms < 2; ++ms)
        #pragma unroll
        for (int ns = 0; ns < 2; ++ns) {
            const int j = n0 + wn * 32 + ns * 16 + l16;
            if (j >= 288) continue;
            const int m = m0 + wm * 32 + ms * 16 + quad * 4;   // C/D: col=lane&15, row=quad*4+reg
            const int bb = m >> 9, tt = m & 511;
            const float4 v = make_float4(acc[ms][ns][0], acc[ms][ns][1], acc[ms][ns][2], acc[ms][ns][3]);
            float* dst;
            if (j < 256)
                dst = Sh + (size_t)((bb * 16 + (j >> 4)) * 16 + (j & 15)) * SROW + 32 + tt;
            else
                dst = VWh + (size_t)(bb * 32 + (j - 256)) * SROW + 32 + tt;
            *(float4*)dst = v;
        }
}

// ---------------- k3: exp + sliding-window softmax + head-reduce ----------------
#define ES 324
__global__ __launch_bounds__(256) void k3(
    const float* __restrict__ S0, const float* __restrict__ S1,
    const float* __restrict__ VW0, const float* __restrict__ VW1,
    const float* __restrict__ brp, float* __restrict__ out)
{
    __shared__ float Es[16 * ES];
    __shared__ float EVs[32 * ES];
    const int b = blockIdx.x, q = blockIdx.y, half = blockIdx.z;
    const int tbase = half * 256;
    const int tid = threadIdx.x;
    for (int idx = tid; idx < 16 * 72; idx += 256) {
        const int h = idx / 72, g = idx - h * 72;
        const size_t off = (size_t)((b * 16 + q) * 16 + h) * SROW + tbase + g * 4;
        const float4 a = *(const float4*)(S0 + off);
        const float4 c = *(const float4*)(S1 + off);
        float4 e;
        e.x = __expf(a.x + c.x); e.y = __expf(a.y + c.y);
        e.z = __expf(a.z + c.z); e.w = __expf(a.w + c.w);
        *(float4*)(Es + h * ES + g * 4) = e;
    }
    __syncthreads();
    for (int idx = tid; idx < 32 * 72; idx += 256) {
        const int hc = idx / 72, g = idx - hc * 72;
        const size_t off = (size_t)(b * 32 + hc) * SROW + tbase + g * 4;
        const float4 v0 = *(const float4*)(VW0 + off);
        const float4 v1 = *(const float4*)(VW1 + off);
        const float4 e = *(const float4*)(Es + (hc >> 1) * ES + g * 4);
        float4 r;
        r.x = e.x * (v0.x + v1.x); r.y = e.y * (v0.y + v1.y);
        r.z = e.z * (v0.z + v1.z); r.w = e.w * (v0.w + v1.w);
        *(float4*)(EVs + hc * ES + g * 4) = r;
    }
    __syncthreads();
    const int h = tid & 15, mg = tid >> 4;
    const float* ep = Es + h * ES + mg * 16;
    const float* e0 = EVs + (2 * h) * ES + mg * 16;
    const float* e1 = EVs + (2 * h + 1) * ES + mg * 16;
    float den = 0.f, n0 = 0.f, n1 = 0.f;
    #pragma unroll
    for (int s = 0; s < 32; ++s) {
        const int ss = 1 + ((s + 2 * h) & 31);
        den += ep[ss]; n0 += e0[ss]; n1 += e1[ss];
    }
    const float br0 = brp[0], br1 = brp[1];
    for (int u = 0; u < 16; ++u) {
        const float inv = 1.f / den;
        float c0 = n0 * inv, c1 = n1 * inv;
        #pragma unroll
        for (int w = 1; w < 16; w <<= 1) {
            c0 += __shfl_xor(c0, w, 64);
            c1 += __shfl_xor(c1, w, 64);
        }
        if (h == 0) {
            const int m = tbase + mg * 16 + u;
            float* o = out + (size_t)((b * 512 + m) * 16 + q) * 2;
            o[0] = c0 + br0;
            o[1] = c1 + br1;
        }
        if (u < 15) {
            den += ep[33 + u] - ep[1 + u];
            n0 += e0[33 + u] - e0[1 + u];
            n1 += e1[33 + u] - e1[1 + u];
        }
    }
}

extern "C" void kernel_launch(void* const* d_in, const int* in_sizes, int n_in,
                              void* d_out, int out_size, void* d_ws, size_t ws_size,
                              hipStream_t stream)
{
    (void)in_sizes; (void)n_in; (void)out_size; (void)ws_size;
    const float* h  = (const float*)d_in[0];
    const float* fc = (const float*)d_in[1];
    const float* fs = (const float*)d_in[2];
    const float* Wq = (const float*)d_in[3];
    const float* Wk = (const float*)d_in[4];
    const float* Wv = (const float*)d_in[5];
    const float* Wo = (const float*)d_in[6];
    const float* oq = (const float*)d_in[7];
    const float* Wr = (const float*)d_in[8];
    const float* br = (const float*)d_in[9];
    float* ws = (float*)d_ws;
    float* Wor  = ws + OFF_WOR;
    float* qr   = ws + OFF_QR;
    unsigned short* Wth = (unsigned short*)(ws + OFF_WTH);
    unsigned short* Wtl = (unsigned short*)(ws + OFF_WTL);
    float* S0   = ws + OFF_S0;
    float* S1   = ws + OFF_S1;
    float* VW0  = ws + OFF_VW0;
    float* VW1  = ws + OFF_VW1;
    float* out = (float*)d_out;

    hipLaunchKernelGGL(kP, dim3(658), dim3(256), 0, stream,
                       oq, Wq, fc, fs, Wo, Wr, qr, Wor, S0, S1, VW0, VW1,
                       (unsigned*)Wth, (unsigned*)Wtl);
    hipLaunchKernelGGL(kW, dim3(128), dim3(256), 0, stream, Wk, Wv, qr, Wor, Wth, Wtl);
    hipLaunchKernelGGL(k2, dim3(64, 5, 2), dim3(256), 0, stream, h, Wth, Wtl, S0, S1, VW0, VW1);
    hipLaunchKernelGGL(k3, dim3(8, 16, 2), dim3(256), 0, stream, S0, S1, VW0, VW1, br, out);
}